// Round 8
// baseline (278.061 us; speedup 1.0000x reference)
//
#include <hip/hip_runtime.h>
#include <hip/hip_bf16.h>
#include <cstdint>

// Problem dims
#define NBATCH 2
#define NS 2048
#define NDIM 1024
#define NHEAD 16
#define NDH 64
#define NBH 32  // NBATCH*NHEAD

typedef __bf16 bf16x8 __attribute__((ext_vector_type(8)));
typedef float f32x4 __attribute__((ext_vector_type(4)));

// exp(x/8) = 2^(x * log2(e)/8); Q is pre-scaled by this in the Q-GEMM epilogue
#define QK_EXP2_SCALE 0.1803368801111244f

#define WAITV(N) asm volatile("s_waitcnt vmcnt(" #N ")" ::: "memory")
#define FENCE asm volatile("" ::: "memory")

static __device__ __forceinline__ f32x4 mfma16(bf16x8 a, bf16x8 b, f32x4 c) {
  return __builtin_amdgcn_mfma_f32_16x16x32_bf16(a, b, c, 0, 0, 0);
}

static __device__ __forceinline__ void gload_lds16(const void* g, void* l) {
  __builtin_amdgcn_global_load_lds(
      (const __attribute__((address_space(1))) uint32_t*)g,
      (__attribute__((address_space(3))) uint32_t*)l, 16, 0, 0);
}

// ---------------------------------------------------------------------------
// Kernel 0b: convert+transpose W -> Wt[n][k] bf16 (y=0..3); y==4: mask->bias.
__global__ __launch_bounds__(256) void k_cvt_w(const float* __restrict__ Wq,
                                               const float* __restrict__ Wk,
                                               const float* __restrict__ Wv,
                                               const float* __restrict__ Wo,
                                               __bf16* __restrict__ out,
                                               const int* __restrict__ mask,
                                               float* __restrict__ biasf) {
  if (blockIdx.y == 4) {
    // softmax additive bias: 0 kept, -1e30 masked.  [2][2048] f32
    int t = blockIdx.x * 256 + threadIdx.x;
    if (t < NBATCH * NS) biasf[t] = mask[t] ? 0.f : -1e30f;
    return;
  }
  const float* W = blockIdx.y == 0 ? Wq : (blockIdx.y == 1 ? Wk
                   : (blockIdx.y == 2 ? Wv : Wo));
  __bf16* dst = out + (size_t)blockIdx.y * (size_t)(1024 * 1024);
  int t = blockIdx.x * 256 + threadIdx.x;  // 0..131071
  int n = t & 1023;
  int kc = t >> 10;  // 0..127
  bf16x8 o;
#pragma unroll
  for (int j = 0; j < 8; ++j) o[j] = (__bf16)W[(size_t)(kc * 8 + j) * 1024 + n];
  *reinterpret_cast<bf16x8*>(dst + (size_t)n * 1024 + kc * 8) = o;
}

// ---------------------------------------------------------------------------
// Fused QKV GEMM: C = X * Wt^T + bias, X fp32 [4096][1024] read directly
// (fp32->bf16 convert fused into A staging: global->reg->cvt->ds_write).
// B (weights) staged via global_load_lds. Double-buffered, barrier per kt.
// job 0 (Q): head layout [(b*16+h)][s][d], scaled by QK_EXP2_SCALE.
// job 1 (K): head layout. job 2 (V): writes V^T [bh][d][s] directly (8B
// vector stores over 4 consecutive s) - the tr_v kernel is folded in here.
__global__ __launch_bounds__(256) void k_gemm_qkv(
    const float* __restrict__ qs, const float* __restrict__ ks,
    const float* __restrict__ vs, const __bf16* __restrict__ Wt,
    const float* __restrict__ bq, const float* __restrict__ bk,
    const float* __restrict__ bv, __bf16* __restrict__ outb) {
  __shared__ __align__(16) char smem[65536];  // [2][A 16K | B 16K]
  const int job = blockIdx.y;
  const float* X = job == 0 ? qs : (job == 1 ? ks : vs);
  const __bf16* Bt = Wt + (size_t)job * (size_t)(1024 * 1024);
  const float* bias = job == 0 ? bq : (job == 1 ? bk : bv);
  // XCD swizzle: xcd = x&7 gets mt = xcd*4 + (x>>6), all 8 nt co-resident
  const int x = blockIdx.x;
  const int mt = (x & 7) * 4 + (x >> 6);  // 0..31
  const int nt = (x >> 3) & 7;            // 0..7
  const int tid = threadIdx.x;
  const int w = tid >> 6, l = tid & 63;
  const int wr = w >> 1, wc = w & 1;
  // staging coords: thread covers rows r0+32i, swizzled k-chunk cs (8 elems)
  const int r0 = tid >> 3;
  const int cs = (tid & 7) ^ (r0 & 7);

  float4 fa[4], fb[4];  // A fp32 in-flight regs

  auto issueS = [&](int buf, int kt) {
    const int k0 = kt * 64;
    char* bl = smem + buf * 32768 + 16384;
#pragma unroll
    for (int i = 0; i < 4; ++i) {
      int r = r0 + 32 * i;
      gload_lds16(Bt + (size_t)(nt * 128 + r) * 1024 + k0 + cs * 8,
                  bl + (tid + i * 256) * 16);
    }
#pragma unroll
    for (int i = 0; i < 4; ++i) {
      const float* src =
          X + (size_t)(mt * 128 + r0 + 32 * i) * 1024 + k0 + cs * 8;
      fa[i] = *reinterpret_cast<const float4*>(src);
      fb[i] = *reinterpret_cast<const float4*>(src + 4);
    }
  };
  auto writeA = [&](int buf) {
    char* al = smem + buf * 32768;
#pragma unroll
    for (int i = 0; i < 4; ++i) {
      bf16x8 o;
      o[0] = (__bf16)fa[i].x; o[1] = (__bf16)fa[i].y;
      o[2] = (__bf16)fa[i].z; o[3] = (__bf16)fa[i].w;
      o[4] = (__bf16)fb[i].x; o[5] = (__bf16)fb[i].y;
      o[6] = (__bf16)fb[i].z; o[7] = (__bf16)fb[i].w;
      *reinterpret_cast<bf16x8*>(al + (tid + i * 256) * 16) = o;
    }
  };

  f32x4 acc[4][4] = {};
  issueS(0, 0);
  for (int kt = 0; kt < 16; ++kt) {
    WAITV(0);          // A(kt) regs + B(kt) LDS landed (overlapped compute)
    writeA(kt & 1);    // buf free: readers (kt-2) done via barrier(kt-1)
    __syncthreads();   // vmcnt already 0 -> cheap; publishes A writes
    if (kt + 1 < 16) issueS((kt + 1) & 1, kt + 1);
    const char* al = smem + (kt & 1) * 32768;
    const char* bl = al + 16384;
#pragma unroll
    for (int ks = 0; ks < 2; ++ks) {
      bf16x8 af[4], bfr[4];
#pragma unroll
      for (int i = 0; i < 4; ++i) {
        int ra = wr * 64 + i * 16 + (l & 15);
        int ca = (ks * 4 + (l >> 4)) ^ (ra & 7);
        af[i] = *reinterpret_cast<const bf16x8*>(al + ra * 128 + ca * 16);
        int rb = wc * 64 + i * 16 + (l & 15);
        int cb = (ks * 4 + (l >> 4)) ^ (rb & 7);
        bfr[i] = *reinterpret_cast<const bf16x8*>(bl + rb * 128 + cb * 16);
      }
#pragma unroll
      for (int mi = 0; mi < 4; ++mi)
#pragma unroll
        for (int ni = 0; ni < 4; ++ni)
          acc[mi][ni] = mfma16(af[mi], bfr[ni], acc[mi][ni]);
    }
  }

  if (job == 2) {
    // V^T epilogue: Vt[bh][d][s], 4 consecutive s per lane -> 8B stores
    __bf16* vt = outb + (size_t)2 * (size_t)(NBH * NS * NDH);
#pragma unroll
    for (int mi = 0; mi < 4; ++mi)
#pragma unroll
      for (int ni = 0; ni < 4; ++ni) {
        int m0 = mt * 128 + wr * 64 + mi * 16 + (l >> 4) * 4;
        int n = nt * 128 + wc * 64 + ni * 16 + (l & 15);
        int b = m0 >> 11, s0 = m0 & 2047, h = n >> 6, d = n & 63;
        union { __bf16 h4[4]; uint2 u; } pk;
#pragma unroll
        for (int r = 0; r < 4; ++r)
          pk.h4[r] = (__bf16)(acc[mi][ni][r] + bias[n]);
        *reinterpret_cast<uint2*>(
            vt + ((size_t)(b * 16 + h) * 64 + d) * 2048 + s0) = pk.u;
      }
  } else {
    const float sc = (job == 0) ? QK_EXP2_SCALE : 1.0f;
    __bf16* outp = outb + (size_t)job * (size_t)(NBH * NS * NDH);
#pragma unroll
    for (int mi = 0; mi < 4; ++mi)
#pragma unroll
      for (int ni = 0; ni < 4; ++ni)
#pragma unroll
        for (int r = 0; r < 4; ++r) {
          int m = mt * 128 + wr * 64 + mi * 16 + (l >> 4) * 4 + r;
          int n = nt * 128 + wc * 64 + ni * 16 + (l & 15);
          float v = (acc[mi][ni][r] + bias[n]) * sc;
          int b = m >> 11, s = m & 2047, h = n >> 6, d = n & 63;
          outp[(((size_t)(b * 16 + h)) * 2048 + s) * 64 + d] = (__bf16)v;
        }
  }
}

// ---------------------------------------------------------------------------
// Out-proj GEMM (round-7 k_gemm, mode fixed to fp32 output).
__global__ __launch_bounds__(256) void k_gemm_o(const __bf16* __restrict__ A,
                                                const __bf16* __restrict__ Bt,
                                                const float* __restrict__ bias,
                                                float* __restrict__ outp) {
  __shared__ __align__(16) char smem[65536];  // [2][A 16K | B 16K]
  const int x = blockIdx.x;
  const int mt = (x & 7) * 4 + (x >> 6);  // 0..31
  const int nt = (x >> 3) & 7;            // 0..7
  const int tid = threadIdx.x;
  const int w = tid >> 6, l = tid & 63;
  const int wr = w >> 1, wc = w & 1;

  auto stage = [&](int buf, int kt) {
    const int k0 = kt * 64;
    char* al = smem + buf * 32768;
    char* bl = al + 16384;
#pragma unroll
    for (int i = 0; i < 4; ++i) {
      int ch = tid + i * 256;  // 0..1023
      int r = ch >> 3, c = ch & 7;
      int cs = c ^ (r & 7);
      gload_lds16(A + (size_t)(mt * 128 + r) * 1024 + k0 + cs * 8, al + ch * 16);
      gload_lds16(Bt + (size_t)(nt * 128 + r) * 1024 + k0 + cs * 8, bl + ch * 16);
    }
  };

  f32x4 acc[4][4] = {};
  stage(0, 0);
  for (int kt = 0; kt < 16; ++kt) {
    __syncthreads();  // implicit vmcnt(0): stage(kt) complete for all waves
    if (kt + 1 < 16) stage((kt + 1) & 1, kt + 1);
    const char* al = smem + (kt & 1) * 32768;
    const char* bl = al + 16384;
#pragma unroll
    for (int ks = 0; ks < 2; ++ks) {
      bf16x8 af[4], bfr[4];
#pragma unroll
      for (int i = 0; i < 4; ++i) {
        int ra = wr * 64 + i * 16 + (l & 15);
        int ca = (ks * 4 + (l >> 4)) ^ (ra & 7);
        af[i] = *reinterpret_cast<const bf16x8*>(al + ra * 128 + ca * 16);
        int rb = wc * 64 + i * 16 + (l & 15);
        int cb = (ks * 4 + (l >> 4)) ^ (rb & 7);
        bfr[i] = *reinterpret_cast<const bf16x8*>(bl + rb * 128 + cb * 16);
      }
#pragma unroll
      for (int mi = 0; mi < 4; ++mi)
#pragma unroll
        for (int ni = 0; ni < 4; ++ni)
          acc[mi][ni] = mfma16(af[mi], bfr[ni], acc[mi][ni]);
    }
  }

#pragma unroll
  for (int mi = 0; mi < 4; ++mi)
#pragma unroll
    for (int ni = 0; ni < 4; ++ni)
#pragma unroll
      for (int r = 0; r < 4; ++r) {
        int m = mt * 128 + wr * 64 + mi * 16 + (l >> 4) * 4 + r;
        int n = nt * 128 + wc * 64 + ni * 16 + (l & 15);
        outp[(size_t)m * 1024 + n] = acc[mi][ni][r] + bias[n];
      }
}

// ---------------------------------------------------------------------------
// Attention v6 (unchanged from round 7): round-4 schedule + coalesced attn
// stores through wave-private Pf32 LDS tile; PV A-fragment read back from it.
// LDS: K dbuf @0/@16K (pass1 ring-3 @0/@16K/@32K), V dbuf @32K/@48K,
//      Pf32 per wave @64K + w*2K (8 KB), bias ring-3 @72K (3x512B).
__global__ __launch_bounds__(256, 2) void k_attn(
    const __bf16* __restrict__ Qw, const __bf16* __restrict__ Kw,
    const __bf16* __restrict__ Vt, const float* __restrict__ biasf,
    float* __restrict__ attn_out, __bf16* __restrict__ ctx_out) {
  __shared__ __align__(16) char smem[75264];
  // XCD swizzle: 512 blocks -> 64 contiguous work items (4 bh) per XCD
  const int wg = blockIdx.x;
  const int swz = (wg & 7) * 64 + (wg >> 3);
  const int qt = swz & 15;  // q-tile of 128
  const int bh = swz >> 4;  // 0..31
  const int b = bh >> 4;
  const int tid = threadIdx.x, w = tid >> 6, l = tid & 63;
  const int g = l >> 4, c = l & 15;
  const int qw = qt * 128 + w * 32;  // this wave's first q row
  const float* biasb = biasf + b * 2048;

  // Q fragments (B-operand): lane holds Q[qw+16mi+c][32ks+8g .. +8]
  bf16x8 qa[2][2];
#pragma unroll
  for (int mi = 0; mi < 2; ++mi)
#pragma unroll
    for (int ks = 0; ks < 2; ++ks)
      qa[mi][ks] = *reinterpret_cast<const bf16x8*>(
          Qw + ((size_t)bh * 2048 + qw + mi * 16 + c) * 64 + ks * 32 + g * 8);

  auto stageK = [&](char* dst, int kt) {
#pragma unroll
    for (int i = 0; i < 4; ++i) {
      int ch = tid + i * 256;  // 0..1023
      int r = ch >> 3, cc = ch & 7;
      int cs = cc ^ (r & 7);
      gload_lds16(Kw + ((size_t)bh * 2048 + kt * 128 + r) * 64 + cs * 8,
                  dst + ch * 16);
    }
  };
  auto stageV = [&](char* dst, int kt) {
#pragma unroll
    for (int i = 0; i < 4; ++i) {
      int ch = tid + i * 256;  // 0..1023
      int r = ch >> 4, cc = ch & 15;
      int cs = cc ^ (r & 15);
      gload_lds16(Vt + ((size_t)bh * 64 + r) * 2048 + kt * 128 + cs * 8,
                  dst + ch * 16);
    }
  };
  // 512 B of per-kt bias; all 4 waves write the same data (benign)
  auto stageBias = [&](int slot, int kt) {
    if (l < 32)
      gload_lds16(biasb + kt * 128 + l * 4, smem + 73728 + slot * 512);
  };

  // ---- Pass 1: masked rowsums of exp2(s+bias); K ring-3, 1 barrier/kt ----
  float rs[2] = {0.f, 0.f};
  stageK(smem, 0);
  stageBias(0, 0);
  int sl = 0;
  for (int kt = 0; kt < 16; ++kt) {
    int nx = (sl + 1 == 3) ? 0 : sl + 1;
    if (kt + 1 < 16) {
      stageK(smem + nx * 16384, kt + 1);
      stageBias(nx, kt + 1);
      WAITV(5);  // FIFO: [stage(kt):5][stage(kt+1):5] -> stage(kt) landed
    } else {
      WAITV(0);
    }
    __builtin_amdgcn_s_barrier();
    FENCE;
    const char* kl = smem + sl * 16384;
    const float* bl = (const float*)(smem + 73728 + sl * 512);
#pragma unroll
    for (int nb = 0; nb < 8; ++nb) {
      bf16x8 kb[2];
#pragma unroll
      for (int ks = 0; ks < 2; ++ks) {
        int r = nb * 16 + c;
        int cc = (ks * 4 + g) ^ (r & 7);
        kb[ks] = *reinterpret_cast<const bf16x8*>(kl + r * 128 + cc * 16);
      }
      f32x4 cinit = *reinterpret_cast<const f32x4*>(bl + nb * 16 + g * 4);
#pragma unroll
      for (int mi = 0; mi < 2; ++mi) {
        f32x4 s = mfma16(kb[0], qa[mi][0], cinit);
        s = mfma16(kb[1], qa[mi][1], s);
        rs[mi] += exp2f(s[0]) + exp2f(s[1]) + exp2f(s[2]) + exp2f(s[3]);
      }
    }
    sl = nx;
  }
  float inv_[2];
#pragma unroll
  for (int mi = 0; mi < 2; ++mi) {
    float v = rs[mi];
    v += __shfl_xor(v, 16, 64);
    v += __shfl_xor(v, 32, 64);
    inv_[mi] = v > 0.f ? 1.f / v : 0.f;
  }
  FENCE; __builtin_amdgcn_s_barrier(); FENCE;  // pass-1 readers done

  // ---- Pass 2: recompute, coalesced attn stores via Pf32 LDS, PV ----
  f32x4 ctx[2][4] = {};
  float* attnb = attn_out + (size_t)bh * 2048 * 2048;
  char* pF = smem + 65536 + w * 2048;  // wave-private P f32 [16 q][32 k]
  stageK(smem, 0);
  stageV(smem + 32768, 0);
  stageBias(0, 0);
  for (int kt = 0; kt < 16; ++kt) {
    if (kt + 1 < 16) {
      int nx3 = (kt + 1) % 3;
      stageK(smem + ((kt + 1) & 1) * 16384, kt + 1);
      stageV(smem + 32768 + ((kt + 1) & 1) * 16384, kt + 1);
      stageBias(nx3, kt + 1);
    }
    // FIFO: [stage(kt):9][stores(kt-1):16][stage(kt+1):9] -> 2-iter slack
    if (kt == 0) WAITV(9);
    else if (kt == 15) WAITV(16);
    else WAITV(25);
    FENCE; __builtin_amdgcn_s_barrier(); FENCE;
    const char* kl = smem + (kt & 1) * 16384;
    const char* vl = smem + 32768 + (kt & 1) * 16384;
    const float* bl = (const float*)(smem + 73728 + (kt % 3) * 512);
#pragma unroll
    for (int kc = 0; kc < 4; ++kc) {
      // hoist K fragments + bias for nb = 2kc, 2kc+1
      bf16x8 kbj[2][2];
      f32x4 cin[2];
#pragma unroll
      for (int j = 0; j < 2; ++j) {
        const int nb = kc * 2 + j;
#pragma unroll
        for (int ks = 0; ks < 2; ++ks) {
          int r = nb * 16 + c;
          int cc = (ks * 4 + g) ^ (r & 7);
          kbj[j][ks] = *reinterpret_cast<const bf16x8*>(kl + r * 128 + cc * 16);
        }
        cin[j] = *reinterpret_cast<const f32x4*>(bl + nb * 16 + g * 4);
      }
      // hoist V fragments for this 32-k chunk
      bf16x8 vb[4];
#pragma unroll
      for (int nd = 0; nd < 4; ++nd) {
        int dd = nd * 16 + c;
        int ch = (kc * 4 + g) ^ (dd & 15);
        vb[nd] = *reinterpret_cast<const bf16x8*>(vl + dd * 256 + ch * 16);
      }
#pragma unroll
      for (int mi = 0; mi < 2; ++mi) {
        // QK + exp -> Pf32 LDS (row c, chunk-XOR swizzle)
#pragma unroll
        for (int j = 0; j < 2; ++j) {
          f32x4 s = mfma16(kbj[j][0], qa[mi][0], cin[j]);
          s = mfma16(kbj[j][1], qa[mi][1], s);
          f32x4 p;
#pragma unroll
          for (int r = 0; r < 4; ++r) p[r] = exp2f(s[r]) * inv_[mi];
          *reinterpret_cast<f32x4*>(
              pF + c * 128 + (((j * 4 + g) ^ (c & 7)) * 16)) = p;
        }
        // PV A-fragment from Pf32 (k = kc*32 + g*8 .. +8), cvt to bf16
        bf16x8 pa;
        {
          f32x4 lo = *reinterpret_cast<const f32x4*>(
              pF + c * 128 + (((2 * g) ^ (c & 7)) * 16));
          f32x4 hi = *reinterpret_cast<const f32x4*>(
              pF + c * 128 + (((2 * g + 1) ^ (c & 7)) * 16));
          pa[0] = (__bf16)lo[0]; pa[1] = (__bf16)lo[1];
          pa[2] = (__bf16)lo[2]; pa[3] = (__bf16)lo[3];
          pa[4] = (__bf16)hi[0]; pa[5] = (__bf16)hi[1];
          pa[6] = (__bf16)hi[2]; pa[7] = (__bf16)hi[3];
        }
#pragma unroll
        for (int nd = 0; nd < 4; ++nd)
          ctx[mi][nd] = mfma16(pa, vb[nd], ctx[mi][nd]);
        // coalesced attn stores: 2 x 1 KB, each 8 rows x 128 B (full lines)
#pragma unroll
        for (int u = 0; u < 2; ++u) {
          int rr = u * 8 + (l >> 3);          // 0..15
          int ch = (l & 7) ^ (rr & 7);
          f32x4 pv = *reinterpret_cast<const f32x4*>(pF + rr * 128 + ch * 16);
          *reinterpret_cast<f32x4*>(
              attnb + (size_t)(qw + mi * 16 + rr) * 2048 + kt * 128 +
              kc * 32 + (l & 7) * 4) = pv;
        }
      }
    }
    FENCE; __builtin_amdgcn_s_barrier(); FENCE;  // protect buf from stage(kt+2)
  }

  // ctx epilogue -> ws as [4096][1024] bf16 (row m = b*2048+s, col n = h*64+d)
  const int h = bh & 15;
#pragma unroll
  for (int mi = 0; mi < 2; ++mi)
#pragma unroll
    for (int nd = 0; nd < 4; ++nd)
#pragma unroll
      for (int r = 0; r < 4; ++r) {
        int m = b * 2048 + qw + mi * 16 + g * 4 + r;
        int n = h * 64 + nd * 16 + c;
        ctx_out[(size_t)m * 1024 + n] = (__bf16)ctx[mi][nd][r];
      }
}

// ---------------------------------------------------------------------------
extern "C" void kernel_launch(void* const* d_in, const int* in_sizes, int n_in,
                              void* d_out, int out_size, void* d_ws,
                              size_t ws_size, hipStream_t stream) {
  const float* qs = (const float*)d_in[0];
  const float* ks = (const float*)d_in[1];
  const float* vs = (const float*)d_in[2];
  const int* mask = (const int*)d_in[3];
  const float* Wq = (const float*)d_in[4];
  const float* bq = (const float*)d_in[5];
  const float* Wk = (const float*)d_in[6];
  const float* bk = (const float*)d_in[7];
  const float* Wv = (const float*)d_in[8];
  const float* bv = (const float*)d_in[9];
  const float* Wo = (const float*)d_in[10];
  const float* bo = (const float*)d_in[11];

  char* ws = (char*)d_ws;
  __bf16* Wt = (__bf16*)(ws);                    // [4][1024][1024] bf16, 8MB
  __bf16* QKV = (__bf16*)(ws + 8388608);         // Q,K head layout; slot 2=V^T
  float* biasf = (float*)(ws + 33554432);        // [2][2048] f32
  __bf16* ctx = (__bf16*)(ws + 33570816);        // [4096][1024] bf16
  float* out = (float*)d_out;
  float* attn = out + (size_t)4194304;

  k_cvt_w<<<dim3(512, 5), 256, 0, stream>>>(Wq, Wk, Wv, Wo, Wt, mask, biasf);
  k_gemm_qkv<<<dim3(256, 3), 256, 0, stream>>>(qs, ks, vs, Wt, bq, bk, bv,
                                               QKV);
  k_attn<<<dim3(512), 256, 0, stream>>>(QKV, QKV + (size_t)4194304,
                                        QKV + (size_t)2 * 4194304, biasf,
                                        attn, ctx);
  k_gemm_o<<<dim3(256), 256, 0, stream>>>(ctx, Wt + (size_t)3 * 1048576, bo,
                                          (float*)d_out);
}

// Round 9
// 250.455 us; speedup vs baseline: 1.1102x; 1.1102x over previous
//
#include <hip/hip_runtime.h>
#include <hip/hip_bf16.h>
#include <cstdint>

// Problem dims
#define NBATCH 2
#define NS 2048
#define NDIM 1024
#define NHEAD 16
#define NDH 64
#define NBH 32  // NBATCH*NHEAD

typedef __bf16 bf16x8 __attribute__((ext_vector_type(8)));
typedef float f32x4 __attribute__((ext_vector_type(4)));

// exp(x/8) = 2^(x * log2(e)/8); Q is pre-scaled by this in the Q-GEMM epilogue
#define QK_EXP2_SCALE 0.1803368801111244f

#define WAITV(N) asm volatile("s_waitcnt vmcnt(" #N ")" ::: "memory")
#define FENCE asm volatile("" ::: "memory")

static __device__ __forceinline__ f32x4 mfma16(bf16x8 a, bf16x8 b, f32x4 c) {
  return __builtin_amdgcn_mfma_f32_16x16x32_bf16(a, b, c, 0, 0, 0);
}

static __device__ __forceinline__ void gload_lds16(const void* g, void* l) {
  __builtin_amdgcn_global_load_lds(
      (const __attribute__((address_space(1))) uint32_t*)g,
      (__attribute__((address_space(3))) uint32_t*)l, 16, 0, 0);
}

// ---------------------------------------------------------------------------
// Kernel 0a: fp32 -> bf16 convert for qs/ks/vs. out: [3][4096][1024] bf16
__global__ __launch_bounds__(256) void k_cvt_x(const float* __restrict__ q,
                                               const float* __restrict__ k,
                                               const float* __restrict__ v,
                                               __bf16* __restrict__ out) {
  const float* src = blockIdx.y == 0 ? q : (blockIdx.y == 1 ? k : v);
  __bf16* dst = out + (size_t)blockIdx.y * (size_t)(4096 * 1024);
  int i = blockIdx.x * 256 + threadIdx.x;  // chunk of 8 floats
  const float4* s4 = reinterpret_cast<const float4*>(src) + (size_t)i * 2;
  float4 a = s4[0], b = s4[1];
  bf16x8 o;
  o[0] = (__bf16)a.x; o[1] = (__bf16)a.y; o[2] = (__bf16)a.z; o[3] = (__bf16)a.w;
  o[4] = (__bf16)b.x; o[5] = (__bf16)b.y; o[6] = (__bf16)b.z; o[7] = (__bf16)b.w;
  *reinterpret_cast<bf16x8*>(dst + (size_t)i * 8) = o;
}

// ---------------------------------------------------------------------------
// Kernel 0b: convert+transpose W -> Wt[n][k] bf16 (y=0..3); y==4: mask->bias.
__global__ __launch_bounds__(256) void k_cvt_w(const float* __restrict__ Wq,
                                               const float* __restrict__ Wk,
                                               const float* __restrict__ Wv,
                                               const float* __restrict__ Wo,
                                               __bf16* __restrict__ out,
                                               const int* __restrict__ mask,
                                               float* __restrict__ biasf) {
  if (blockIdx.y == 4) {
    // softmax additive bias: 0 kept, -1e30 masked.  [2][2048] f32
    int t = blockIdx.x * 256 + threadIdx.x;
    if (t < NBATCH * NS) biasf[t] = mask[t] ? 0.f : -1e30f;
    return;
  }
  const float* W = blockIdx.y == 0 ? Wq : (blockIdx.y == 1 ? Wk
                   : (blockIdx.y == 2 ? Wv : Wo));
  __bf16* dst = out + (size_t)blockIdx.y * (size_t)(1024 * 1024);
  int t = blockIdx.x * 256 + threadIdx.x;  // 0..131071
  int n = t & 1023;
  int kc = t >> 10;  // 0..127
  bf16x8 o;
#pragma unroll
  for (int j = 0; j < 8; ++j) o[j] = (__bf16)W[(size_t)(kc * 8 + j) * 1024 + n];
  *reinterpret_cast<bf16x8*>(dst + (size_t)n * 1024 + kc * 8) = o;
}

// ---------------------------------------------------------------------------
// Kernel 0c: transpose V per head: [32][2048][64] bf16 -> Vt [32][64][2048]
__global__ __launch_bounds__(256) void k_tr_v(const __bf16* __restrict__ V,
                                              __bf16* __restrict__ Vt) {
  int t = blockIdx.x * 256 + threadIdx.x;  // 0..524287
  int d = t & 63;
  int sc = (t >> 6) & 255;  // s-chunk of 8
  int bh = t >> 14;         // 0..31
  bf16x8 o;
#pragma unroll
  for (int j = 0; j < 8; ++j)
    o[j] = V[((size_t)bh * 2048 + sc * 8 + j) * 64 + d];
  *reinterpret_cast<bf16x8*>(Vt + ((size_t)bh * 64 + d) * 2048 + sc * 8) = o;
}

// ---------------------------------------------------------------------------
// GEMM: C[4096][1024] = A[4096][1024] * Bt^T + bias.  A row-major [m][k],
// Bt is [n][k] (k contiguous). 128x128 tile, BK=64, 4 waves, dbuf LDS.
// XCD-swizzled: blocks sharing an A-panel are co-resident on one XCD.
// mode 0: write bf16 to head layout [(b*16+h)][s][d], out + job*4194304;
//         job 0 (Q) additionally scaled by QK_EXP2_SCALE.
// mode 1: write fp32 row-major [m][n] (final output)
__global__ __launch_bounds__(256) void k_gemm(const __bf16* __restrict__ Abase,
                                              const __bf16* __restrict__ Btbase,
                                              const float* __restrict__ b0,
                                              const float* __restrict__ b1,
                                              const float* __restrict__ b2,
                                              void* __restrict__ outbase,
                                              int mode) {
  __shared__ __align__(16) char smem[65536];  // [2][A 16K | B 16K]
  const int job = blockIdx.y;
  const __bf16* A = Abase + (size_t)job * (size_t)(4096 * 1024);
  const __bf16* Bt = Btbase + (size_t)job * (size_t)(1024 * 1024);
  const float* bias = job == 0 ? b0 : (job == 1 ? b1 : b2);
  // XCD swizzle: xcd = x&7 gets mt = xcd*4 + (x>>6), all 8 nt co-resident
  const int x = blockIdx.x;
  const int mt = (x & 7) * 4 + (x >> 6);  // 0..31
  const int nt = (x >> 3) & 7;            // 0..7
  const int tid = threadIdx.x;
  const int w = tid >> 6, l = tid & 63;
  const int wr = w >> 1, wc = w & 1;

  auto stage = [&](int buf, int kt) {
    const int k0 = kt * 64;
    char* al = smem + buf * 32768;
    char* bl = al + 16384;
#pragma unroll
    for (int i = 0; i < 4; ++i) {
      int ch = tid + i * 256;  // 0..1023
      int r = ch >> 3, c = ch & 7;
      int cs = c ^ (r & 7);
      gload_lds16(A + (size_t)(mt * 128 + r) * 1024 + k0 + cs * 8, al + ch * 16);
      gload_lds16(Bt + (size_t)(nt * 128 + r) * 1024 + k0 + cs * 8, bl + ch * 16);
    }
  };

  f32x4 acc[4][4] = {};
  stage(0, 0);
  for (int kt = 0; kt < 16; ++kt) {
    __syncthreads();  // implicit vmcnt(0): stage(kt) complete for all waves
    if (kt + 1 < 16) stage((kt + 1) & 1, kt + 1);
    const char* al = smem + (kt & 1) * 32768;
    const char* bl = al + 16384;
#pragma unroll
    for (int ks = 0; ks < 2; ++ks) {
      bf16x8 af[4], bfr[4];
#pragma unroll
      for (int i = 0; i < 4; ++i) {
        int ra = wr * 64 + i * 16 + (l & 15);
        int ca = (ks * 4 + (l >> 4)) ^ (ra & 7);
        af[i] = *reinterpret_cast<const bf16x8*>(al + ra * 128 + ca * 16);
        int rb = wc * 64 + i * 16 + (l & 15);
        int cb = (ks * 4 + (l >> 4)) ^ (rb & 7);
        bfr[i] = *reinterpret_cast<const bf16x8*>(bl + rb * 128 + cb * 16);
      }
#pragma unroll
      for (int mi = 0; mi < 4; ++mi)
#pragma unroll
        for (int ni = 0; ni < 4; ++ni)
          acc[mi][ni] = mfma16(af[mi], bfr[ni], acc[mi][ni]);
    }
  }

  if (mode == 0) {
    const float sc = (job == 0) ? QK_EXP2_SCALE : 1.0f;
    __bf16* outp = (__bf16*)outbase + (size_t)job * (size_t)(NBH * NS * NDH);
#pragma unroll
    for (int mi = 0; mi < 4; ++mi)
#pragma unroll
      for (int ni = 0; ni < 4; ++ni)
#pragma unroll
        for (int r = 0; r < 4; ++r) {
          int m = mt * 128 + wr * 64 + mi * 16 + (l >> 4) * 4 + r;
          int n = nt * 128 + wc * 64 + ni * 16 + (l & 15);
          float v = (acc[mi][ni][r] + bias[n]) * sc;
          int b = m >> 11, s = m & 2047, h = n >> 6, d = n & 63;
          outp[(((size_t)(b * 16 + h)) * 2048 + s) * 64 + d] = (__bf16)v;
        }
  } else {
    float* outp = (float*)outbase;
#pragma unroll
    for (int mi = 0; mi < 4; ++mi)
#pragma unroll
      for (int ni = 0; ni < 4; ++ni)
#pragma unroll
        for (int r = 0; r < 4; ++r) {
          int m = mt * 128 + wr * 64 + mi * 16 + (l >> 4) * 4 + r;
          int n = nt * 128 + wc * 64 + ni * 16 + (l & 15);
          outp[(size_t)m * 1024 + n] = acc[mi][ni][r] + bias[n];
        }
  }
}

// ---------------------------------------------------------------------------
// Attention v7: 512 threads (8 waves x 16 q rows), q-tile 128, 512 blocks
// (XCD-swizzled), 1 block/CU. Pf32 per wave is a FULL kt strip [16q][128k]
// f32 (8 KB) so attn stores are emitted as 512 B-per-row bursts (4x128 B
// consecutive-address instructions per row) for DRAM row locality.
// Counted vmcnt FIFO: stage=5 ops (K2+V2+bias1), stores=8 -> steady WAITV(13).
// LDS (129.5 KB): K dbuf @0/@16K (pass1 ring-3 @0/16K/32K), V dbuf @32K/@48K,
//   Pf32 @64K + w*8K (64 KB), bias @128K (3x512B ring / 2-slot dbuf).
__global__ __launch_bounds__(512, 1) void k_attn(
    const __bf16* __restrict__ Qw, const __bf16* __restrict__ Kw,
    const __bf16* __restrict__ Vt, const float* __restrict__ biasf,
    float* __restrict__ attn_out, __bf16* __restrict__ ctx_out) {
  __shared__ __align__(16) char smem[132608];
  // XCD swizzle: 512 blocks -> 64 contiguous work items (4 bh) per XCD
  const int wg = blockIdx.x;
  const int swz = (wg & 7) * 64 + (wg >> 3);
  const int qt = swz & 15;  // q-tile of 128
  const int bh = swz >> 4;  // 0..31
  const int b = bh >> 4;
  const int tid = threadIdx.x, w = tid >> 6, l = tid & 63;
  const int g = l >> 4, c = l & 15;
  const int qw = qt * 128 + w * 16;  // this wave's first q row
  const float* biasb = biasf + b * 2048;

  // Q fragments (B-operand): lane holds Q[qw+c][32ks+8g .. +8]
  bf16x8 qa[2];
#pragma unroll
  for (int ks = 0; ks < 2; ++ks)
    qa[ks] = *reinterpret_cast<const bf16x8*>(
        Qw + ((size_t)bh * 2048 + qw + c) * 64 + ks * 32 + g * 8);

  auto stageK = [&](char* dst, int kt) {
#pragma unroll
    for (int i = 0; i < 2; ++i) {
      int ch = tid + i * 512;  // 0..1023
      int r = ch >> 3, cc = ch & 7;
      int cs = cc ^ (r & 7);
      gload_lds16(Kw + ((size_t)bh * 2048 + kt * 128 + r) * 64 + cs * 8,
                  dst + ch * 16);
    }
  };
  auto stageV = [&](char* dst, int kt) {
#pragma unroll
    for (int i = 0; i < 2; ++i) {
      int ch = tid + i * 512;  // 0..1023
      int r = ch >> 4, cc = ch & 15;
      int cs = cc ^ (r & 15);
      gload_lds16(Vt + ((size_t)bh * 64 + r) * 2048 + kt * 128 + cs * 8,
                  dst + ch * 16);
    }
  };
  // 512 B of per-kt bias; all 8 waves write the same data (benign, uniform
  // vmcnt: the instruction issues in every wave with lanes 0-31 active)
  auto stageBias = [&](int slot, int kt) {
    if (l < 32)
      gload_lds16(biasb + kt * 128 + l * 4, smem + 131072 + slot * 512);
  };

  // ---- Pass 1: masked rowsums of exp2(s+bias); K ring-3, 1 barrier/kt ----
  float rs = 0.f;
  stageK(smem, 0);
  stageBias(0, 0);
  int sl = 0;
  for (int kt = 0; kt < 16; ++kt) {
    int nx = (sl + 1 == 3) ? 0 : sl + 1;
    if (kt + 1 < 16) {
      stageK(smem + nx * 16384, kt + 1);
      stageBias(nx, kt + 1);
      WAITV(3);  // FIFO: [stage(kt):3][stage(kt+1):3] -> stage(kt) landed
    } else {
      WAITV(0);
    }
    __builtin_amdgcn_s_barrier();
    FENCE;
    const char* kl = smem + sl * 16384;
    const float* bl = (const float*)(smem + 131072 + sl * 512);
#pragma unroll
    for (int nb = 0; nb < 8; ++nb) {
      bf16x8 kb[2];
#pragma unroll
      for (int ks = 0; ks < 2; ++ks) {
        int r = nb * 16 + c;
        int cc = (ks * 4 + g) ^ (r & 7);
        kb[ks] = *reinterpret_cast<const bf16x8*>(kl + r * 128 + cc * 16);
      }
      f32x4 cinit = *reinterpret_cast<const f32x4*>(bl + nb * 16 + g * 4);
      f32x4 s = mfma16(kb[0], qa[0], cinit);
      s = mfma16(kb[1], qa[1], s);
      rs += exp2f(s[0]) + exp2f(s[1]) + exp2f(s[2]) + exp2f(s[3]);
    }
    sl = nx;
  }
  float inv_;
  {
    float v = rs;
    v += __shfl_xor(v, 16, 64);
    v += __shfl_xor(v, 32, 64);
    inv_ = v > 0.f ? 1.f / v : 0.f;
  }
  FENCE; __builtin_amdgcn_s_barrier(); FENCE;  // pass-1 readers done

  // ---- Pass 2: recompute, Pf32 strip, burst stores (512 B/row), PV ----
  f32x4 ctx[4] = {};
  float* attnb = attn_out + (size_t)bh * 2048 * 2048;
  // wave-private P f32 [16 q][128 k]; 16B-chunk index XOR-swizzled by (q&7)
  char* pF = smem + 65536 + w * 8192;
  stageK(smem, 0);
  stageV(smem + 32768, 0);
  stageBias(0, 0);
  for (int kt = 0; kt < 16; ++kt) {
    if (kt + 1 < 16) {
      stageK(smem + ((kt + 1) & 1) * 16384, kt + 1);
      stageV(smem + 32768 + ((kt + 1) & 1) * 16384, kt + 1);
      stageBias((kt + 1) & 1, kt + 1);
    }
    // FIFO: [stage(kt):5][stores(kt-1):8][stage(kt+1):5] -> wait stage(kt)
    if (kt == 0) WAITV(5);
    else if (kt == 15) WAITV(8);
    else WAITV(13);
    FENCE; __builtin_amdgcn_s_barrier(); FENCE;
    const char* kl = smem + (kt & 1) * 16384;
    const char* vl = smem + 32768 + (kt & 1) * 16384;
    const float* bl = (const float*)(smem + 131072 + (kt & 1) * 512);
#pragma unroll
    for (int kc = 0; kc < 4; ++kc) {
      // QK + exp -> Pf32 strip for nb = 2kc, 2kc+1
#pragma unroll
      for (int j = 0; j < 2; ++j) {
        const int nb = kc * 2 + j;
        bf16x8 kb[2];
#pragma unroll
        for (int ks = 0; ks < 2; ++ks) {
          int r = nb * 16 + c;
          int cc = (ks * 4 + g) ^ (r & 7);
          kb[ks] = *reinterpret_cast<const bf16x8*>(kl + r * 128 + cc * 16);
        }
        f32x4 cinit = *reinterpret_cast<const f32x4*>(bl + nb * 16 + g * 4);
        f32x4 s = mfma16(kb[0], qa[0], cinit);
        s = mfma16(kb[1], qa[1], s);
        f32x4 p;
#pragma unroll
        for (int r = 0; r < 4; ++r) p[r] = exp2f(s[r]) * inv_;
        // lane holds k = nb*16 + g*4 .. +4 of row q=c -> chunk nb*4+g
        *reinterpret_cast<f32x4*>(
            pF + c * 512 + (((nb * 4 + g) ^ (c & 7)) * 16)) = p;
      }
      // PV A-fragment from Pf32 (k = kc*32 + g*8 .. +8), cvt to bf16
      bf16x8 pa;
      {
        f32x4 lo = *reinterpret_cast<const f32x4*>(
            pF + c * 512 + (((kc * 8 + g * 2) ^ (c & 7)) * 16));
        f32x4 hi = *reinterpret_cast<const f32x4*>(
            pF + c * 512 + (((kc * 8 + g * 2 + 1) ^ (c & 7)) * 16));
        pa[0] = (__bf16)lo[0]; pa[1] = (__bf16)lo[1];
        pa[2] = (__bf16)lo[2]; pa[3] = (__bf16)lo[3];
        pa[4] = (__bf16)hi[0]; pa[5] = (__bf16)hi[1];
        pa[6] = (__bf16)hi[2]; pa[7] = (__bf16)hi[3];
      }
      bf16x8 vb[4];
#pragma unroll
      for (int nd = 0; nd < 4; ++nd) {
        int dd = nd * 16 + c;
        int ch = (kc * 4 + g) ^ (dd & 15);
        vb[nd] = *reinterpret_cast<const bf16x8*>(vl + dd * 256 + ch * 16);
      }
#pragma unroll
      for (int nd = 0; nd < 4; ++nd)
        ctx[nd] = mfma16(pa, vb[nd], ctx[nd]);
    }
    // Burst stores: rows rg*8..+8; per row 4 consecutive 128 B chunks
#pragma unroll
    for (int rg = 0; rg < 2; ++rg) {
      const int row = rg * 8 + (l >> 3);
#pragma unroll
      for (int cc = 0; cc < 4; ++cc) {
        int chunk = (cc * 8 + (l & 7)) ^ (row & 7);
        f32x4 pv = *reinterpret_cast<const f32x4*>(pF + row * 512 + chunk * 16);
        *reinterpret_cast<f32x4*>(
            attnb + (size_t)(qw + row) * 2048 + kt * 128 + cc * 32 +
            (l & 7) * 4) = pv;
      }
    }
    FENCE; __builtin_amdgcn_s_barrier(); FENCE;  // protect buf from stage(kt+2)
  }

  // ctx epilogue -> ws as [4096][1024] bf16 (row m = b*2048+s, col n = h*64+d)
  const int h = bh & 15;
#pragma unroll
  for (int nd = 0; nd < 4; ++nd)
#pragma unroll
    for (int r = 0; r < 4; ++r) {
      int m = b * 2048 + qw + g * 4 + r;
      int n = h * 64 + nd * 16 + c;
      ctx_out[(size_t)m * 1024 + n] = (__bf16)ctx[nd][r];
    }
}

// ---------------------------------------------------------------------------
extern "C" void kernel_launch(void* const* d_in, const int* in_sizes, int n_in,
                              void* d_out, int out_size, void* d_ws,
                              size_t ws_size, hipStream_t stream) {
  const float* qs = (const float*)d_in[0];
  const float* ks = (const float*)d_in[1];
  const float* vs = (const float*)d_in[2];
  const int* mask = (const int*)d_in[3];
  const float* Wq = (const float*)d_in[4];
  const float* bq = (const float*)d_in[5];
  const float* Wk = (const float*)d_in[6];
  const float* bk = (const float*)d_in[7];
  const float* Wv = (const float*)d_in[8];
  const float* bv = (const float*)d_in[9];
  const float* Wo = (const float*)d_in[10];
  const float* bo = (const float*)d_in[11];

  char* ws = (char*)d_ws;
  __bf16* Xb = (__bf16*)(ws);                    // [3][4096][1024] bf16
  __bf16* Wt = (__bf16*)(ws + 25165824);         // [4][1024][1024] bf16
  __bf16* QKV = (__bf16*)(ws + 58720256);        // [3][32][2048][64] bf16
  float* biasf = (float*)(ws + 83886080);        // [2][2048] f32
  __bf16* Vt = (__bf16*)(ws);                    // reuse X: [32][64][2048]
  __bf16* ctx = (__bf16*)(ws + 8388608);         // reuse X: [4096][1024]
  float* out = (float*)d_out;
  float* attn = out + (size_t)4194304;

  k_cvt_x<<<dim3(2048, 3), 256, 0, stream>>>(qs, ks, vs, Xb);
  k_cvt_w<<<dim3(512, 5), 256, 0, stream>>>(Wq, Wk, Wv, Wo, Wt, mask, biasf);
  k_gemm<<<dim3(256, 3), 256, 0, stream>>>(Xb, Wt, bq, bk, bv, QKV, 0);
  k_tr_v<<<dim3(2048), 256, 0, stream>>>(QKV + (size_t)2 * 4194304, Vt);
  k_attn<<<dim3(512), 512, 0, stream>>>(QKV, QKV + (size_t)4194304, Vt, biasf,
                                        attn, ctx);
  k_gemm<<<dim3(256, 1), 256, 0, stream>>>(ctx, Wt + (size_t)3 * 1048576, bo,
                                           bo, bo, d_out, 1);
}

// Round 10
// 225.616 us; speedup vs baseline: 1.2325x; 1.1101x over previous
//
#include <hip/hip_runtime.h>
#include <hip/hip_bf16.h>
#include <cstdint>

// Problem dims
#define NBATCH 2
#define NS 2048
#define NDIM 1024
#define NHEAD 16
#define NDH 64
#define NBH 32  // NBATCH*NHEAD

typedef __bf16 bf16x8 __attribute__((ext_vector_type(8)));
typedef float f32x4 __attribute__((ext_vector_type(4)));

// exp(x/8) = 2^(x * log2(e)/8); Q is pre-scaled by this in the Q-GEMM epilogue
#define QK_EXP2_SCALE 0.1803368801111244f

#define WAITV(N) asm volatile("s_waitcnt vmcnt(" #N ")" ::: "memory")
#define FENCE asm volatile("" ::: "memory")

static __device__ __forceinline__ f32x4 mfma16(bf16x8 a, bf16x8 b, f32x4 c) {
  return __builtin_amdgcn_mfma_f32_16x16x32_bf16(a, b, c, 0, 0, 0);
}

static __device__ __forceinline__ void gload_lds16(const void* g, void* l) {
  __builtin_amdgcn_global_load_lds(
      (const __attribute__((address_space(1))) uint32_t*)g,
      (__attribute__((address_space(3))) uint32_t*)l, 16, 0, 0);
}

// ---------------------------------------------------------------------------
// Kernel 0a: fp32 -> bf16 convert for qs/ks/vs. out: [3][4096][1024] bf16
__global__ __launch_bounds__(256) void k_cvt_x(const float* __restrict__ q,
                                               const float* __restrict__ k,
                                               const float* __restrict__ v,
                                               __bf16* __restrict__ out) {
  const float* src = blockIdx.y == 0 ? q : (blockIdx.y == 1 ? k : v);
  __bf16* dst = out + (size_t)blockIdx.y * (size_t)(4096 * 1024);
  int i = blockIdx.x * 256 + threadIdx.x;  // chunk of 8 floats
  const float4* s4 = reinterpret_cast<const float4*>(src) + (size_t)i * 2;
  float4 a = s4[0], b = s4[1];
  bf16x8 o;
  o[0] = (__bf16)a.x; o[1] = (__bf16)a.y; o[2] = (__bf16)a.z; o[3] = (__bf16)a.w;
  o[4] = (__bf16)b.x; o[5] = (__bf16)b.y; o[6] = (__bf16)b.z; o[7] = (__bf16)b.w;
  *reinterpret_cast<bf16x8*>(dst + (size_t)i * 8) = o;
}

// ---------------------------------------------------------------------------
// Kernel 0b: convert+transpose W -> Wt[n][k] bf16 (y=0..3); y==4: mask->bias.
__global__ __launch_bounds__(256) void k_cvt_w(const float* __restrict__ Wq,
                                               const float* __restrict__ Wk,
                                               const float* __restrict__ Wv,
                                               const float* __restrict__ Wo,
                                               __bf16* __restrict__ out,
                                               const int* __restrict__ mask,
                                               float* __restrict__ biasf) {
  if (blockIdx.y == 4) {
    // softmax additive bias: 0 kept, -1e30 masked.  [2][2048] f32
    int t = blockIdx.x * 256 + threadIdx.x;
    if (t < NBATCH * NS) biasf[t] = mask[t] ? 0.f : -1e30f;
    return;
  }
  const float* W = blockIdx.y == 0 ? Wq : (blockIdx.y == 1 ? Wk
                   : (blockIdx.y == 2 ? Wv : Wo));
  __bf16* dst = out + (size_t)blockIdx.y * (size_t)(1024 * 1024);
  int t = blockIdx.x * 256 + threadIdx.x;  // 0..131071
  int n = t & 1023;
  int kc = t >> 10;  // 0..127
  bf16x8 o;
#pragma unroll
  for (int j = 0; j < 8; ++j) o[j] = (__bf16)W[(size_t)(kc * 8 + j) * 1024 + n];
  *reinterpret_cast<bf16x8*>(dst + (size_t)n * 1024 + kc * 8) = o;
}

// ---------------------------------------------------------------------------
// Kernel 0c: transpose V per head: [32][2048][64] bf16 -> Vt [32][64][2048]
__global__ __launch_bounds__(256) void k_tr_v(const __bf16* __restrict__ V,
                                              __bf16* __restrict__ Vt) {
  int t = blockIdx.x * 256 + threadIdx.x;  // 0..524287
  int d = t & 63;
  int sc = (t >> 6) & 255;  // s-chunk of 8
  int bh = t >> 14;         // 0..31
  bf16x8 o;
#pragma unroll
  for (int j = 0; j < 8; ++j)
    o[j] = V[((size_t)bh * 2048 + sc * 8 + j) * 64 + d];
  *reinterpret_cast<bf16x8*>(Vt + ((size_t)bh * 64 + d) * 2048 + sc * 8) = o;
}

// ---------------------------------------------------------------------------
// GEMM: C[4096][1024] = A[4096][1024] * Bt^T + bias.  A row-major [m][k],
// Bt is [n][k] (k contiguous). 128x128 tile, BK=64, 4 waves, dbuf LDS.
// XCD-swizzled: blocks sharing an A-panel are co-resident on one XCD.
// mode 0: write bf16 to head layout [(b*16+h)][s][d], out + job*4194304;
//         job 0 (Q) additionally scaled by QK_EXP2_SCALE.
// mode 1: write fp32 row-major [m][n] (final output)
__global__ __launch_bounds__(256) void k_gemm(const __bf16* __restrict__ Abase,
                                              const __bf16* __restrict__ Btbase,
                                              const float* __restrict__ b0,
                                              const float* __restrict__ b1,
                                              const float* __restrict__ b2,
                                              void* __restrict__ outbase,
                                              int mode) {
  __shared__ __align__(16) char smem[65536];  // [2][A 16K | B 16K]
  const int job = blockIdx.y;
  const __bf16* A = Abase + (size_t)job * (size_t)(4096 * 1024);
  const __bf16* Bt = Btbase + (size_t)job * (size_t)(1024 * 1024);
  const float* bias = job == 0 ? b0 : (job == 1 ? b1 : b2);
  // XCD swizzle: xcd = x&7 gets mt = xcd*4 + (x>>6), all 8 nt co-resident
  const int x = blockIdx.x;
  const int mt = (x & 7) * 4 + (x >> 6);  // 0..31
  const int nt = (x >> 3) & 7;            // 0..7
  const int tid = threadIdx.x;
  const int w = tid >> 6, l = tid & 63;
  const int wr = w >> 1, wc = w & 1;

  auto stage = [&](int buf, int kt) {
    const int k0 = kt * 64;
    char* al = smem + buf * 32768;
    char* bl = al + 16384;
#pragma unroll
    for (int i = 0; i < 4; ++i) {
      int ch = tid + i * 256;  // 0..1023
      int r = ch >> 3, c = ch & 7;
      int cs = c ^ (r & 7);
      gload_lds16(A + (size_t)(mt * 128 + r) * 1024 + k0 + cs * 8, al + ch * 16);
      gload_lds16(Bt + (size_t)(nt * 128 + r) * 1024 + k0 + cs * 8, bl + ch * 16);
    }
  };

  f32x4 acc[4][4] = {};
  stage(0, 0);
  for (int kt = 0; kt < 16; ++kt) {
    __syncthreads();  // implicit vmcnt(0): stage(kt) complete for all waves
    if (kt + 1 < 16) stage((kt + 1) & 1, kt + 1);
    const char* al = smem + (kt & 1) * 32768;
    const char* bl = al + 16384;
#pragma unroll
    for (int ks = 0; ks < 2; ++ks) {
      bf16x8 af[4], bfr[4];
#pragma unroll
      for (int i = 0; i < 4; ++i) {
        int ra = wr * 64 + i * 16 + (l & 15);
        int ca = (ks * 4 + (l >> 4)) ^ (ra & 7);
        af[i] = *reinterpret_cast<const bf16x8*>(al + ra * 128 + ca * 16);
        int rb = wc * 64 + i * 16 + (l & 15);
        int cb = (ks * 4 + (l >> 4)) ^ (rb & 7);
        bfr[i] = *reinterpret_cast<const bf16x8*>(bl + rb * 128 + cb * 16);
      }
#pragma unroll
      for (int mi = 0; mi < 4; ++mi)
#pragma unroll
        for (int ni = 0; ni < 4; ++ni)
          acc[mi][ni] = mfma16(af[mi], bfr[ni], acc[mi][ni]);
    }
  }

  if (mode == 0) {
    const float sc = (job == 0) ? QK_EXP2_SCALE : 1.0f;
    __bf16* outp = (__bf16*)outbase + (size_t)job * (size_t)(NBH * NS * NDH);
#pragma unroll
    for (int mi = 0; mi < 4; ++mi)
#pragma unroll
      for (int ni = 0; ni < 4; ++ni)
#pragma unroll
        for (int r = 0; r < 4; ++r) {
          int m = mt * 128 + wr * 64 + mi * 16 + (l >> 4) * 4 + r;
          int n = nt * 128 + wc * 64 + ni * 16 + (l & 15);
          float v = (acc[mi][ni][r] + bias[n]) * sc;
          int b = m >> 11, s = m & 2047, h = n >> 6, d = n & 63;
          outp[(((size_t)(b * 16 + h)) * 2048 + s) * 64 + d] = (__bf16)v;
        }
  } else {
    float* outp = (float*)outbase;
#pragma unroll
    for (int mi = 0; mi < 4; ++mi)
#pragma unroll
      for (int ni = 0; ni < 4; ++ni)
#pragma unroll
        for (int r = 0; r < 4; ++r) {
          int m = mt * 128 + wr * 64 + mi * 16 + (l >> 4) * 4 + r;
          int n = nt * 128 + wc * 64 + ni * 16 + (l & 15);
          outp[(size_t)m * 1024 + n] = acc[mi][ni][r] + bias[n];
        }
  }
}

// ---------------------------------------------------------------------------
// Attention v8 = round-7 v6 + NON-TEMPORAL attn stores (nt bypasses L2 so the
// 537 MB stream stops evicting the L2-resident K/V tiles that 16 q-tile
// blocks per head re-read).
// Schedule: stage-before-wait, counted vmcnt (2-iteration store slack),
// 2 barriers/kt; coalesced stores through wave-private Pf32 LDS tile.
// LDS: K dbuf @0/@16K (pass1 ring-3 @0/@16K/@32K), V dbuf @32K/@48K,
//      Pf32 per wave @64K + w*2K (8 KB), bias ring-3 @72K (3x512B).
__global__ __launch_bounds__(256, 2) void k_attn(
    const __bf16* __restrict__ Qw, const __bf16* __restrict__ Kw,
    const __bf16* __restrict__ Vt, const float* __restrict__ biasf,
    float* __restrict__ attn_out, __bf16* __restrict__ ctx_out) {
  __shared__ __align__(16) char smem[75264];
  // XCD swizzle: 512 blocks -> 64 contiguous work items (4 bh) per XCD
  const int wg = blockIdx.x;
  const int swz = (wg & 7) * 64 + (wg >> 3);
  const int qt = swz & 15;  // q-tile of 128
  const int bh = swz >> 4;  // 0..31
  const int b = bh >> 4;
  const int tid = threadIdx.x, w = tid >> 6, l = tid & 63;
  const int g = l >> 4, c = l & 15;
  const int qw = qt * 128 + w * 32;  // this wave's first q row
  const float* biasb = biasf + b * 2048;

  // Q fragments (B-operand): lane holds Q[qw+16mi+c][32ks+8g .. +8]
  bf16x8 qa[2][2];
#pragma unroll
  for (int mi = 0; mi < 2; ++mi)
#pragma unroll
    for (int ks = 0; ks < 2; ++ks)
      qa[mi][ks] = *reinterpret_cast<const bf16x8*>(
          Qw + ((size_t)bh * 2048 + qw + mi * 16 + c) * 64 + ks * 32 + g * 8);

  auto stageK = [&](char* dst, int kt) {
#pragma unroll
    for (int i = 0; i < 4; ++i) {
      int ch = tid + i * 256;  // 0..1023
      int r = ch >> 3, cc = ch & 7;
      int cs = cc ^ (r & 7);
      gload_lds16(Kw + ((size_t)bh * 2048 + kt * 128 + r) * 64 + cs * 8,
                  dst + ch * 16);
    }
  };
  auto stageV = [&](char* dst, int kt) {
#pragma unroll
    for (int i = 0; i < 4; ++i) {
      int ch = tid + i * 256;  // 0..1023
      int r = ch >> 4, cc = ch & 15;
      int cs = cc ^ (r & 15);
      gload_lds16(Vt + ((size_t)bh * 64 + r) * 2048 + kt * 128 + cs * 8,
                  dst + ch * 16);
    }
  };
  // 512 B of per-kt bias; all 4 waves write the same data (benign)
  auto stageBias = [&](int slot, int kt) {
    if (l < 32)
      gload_lds16(biasb + kt * 128 + l * 4, smem + 73728 + slot * 512);
  };

  // ---- Pass 1: masked rowsums of exp2(s+bias); K ring-3, 1 barrier/kt ----
  float rs[2] = {0.f, 0.f};
  stageK(smem, 0);
  stageBias(0, 0);
  int sl = 0;
  for (int kt = 0; kt < 16; ++kt) {
    int nx = (sl + 1 == 3) ? 0 : sl + 1;
    if (kt + 1 < 16) {
      stageK(smem + nx * 16384, kt + 1);
      stageBias(nx, kt + 1);
      WAITV(5);  // FIFO: [stage(kt):5][stage(kt+1):5] -> stage(kt) landed
    } else {
      WAITV(0);
    }
    __builtin_amdgcn_s_barrier();
    FENCE;
    const char* kl = smem + sl * 16384;
    const float* bl = (const float*)(smem + 73728 + sl * 512);
#pragma unroll
    for (int nb = 0; nb < 8; ++nb) {
      bf16x8 kb[2];
#pragma unroll
      for (int ks = 0; ks < 2; ++ks) {
        int r = nb * 16 + c;
        int cc = (ks * 4 + g) ^ (r & 7);
        kb[ks] = *reinterpret_cast<const bf16x8*>(kl + r * 128 + cc * 16);
      }
      f32x4 cinit = *reinterpret_cast<const f32x4*>(bl + nb * 16 + g * 4);
#pragma unroll
      for (int mi = 0; mi < 2; ++mi) {
        f32x4 s = mfma16(kb[0], qa[mi][0], cinit);
        s = mfma16(kb[1], qa[mi][1], s);
        rs[mi] += exp2f(s[0]) + exp2f(s[1]) + exp2f(s[2]) + exp2f(s[3]);
      }
    }
    sl = nx;
  }
  float inv_[2];
#pragma unroll
  for (int mi = 0; mi < 2; ++mi) {
    float v = rs[mi];
    v += __shfl_xor(v, 16, 64);
    v += __shfl_xor(v, 32, 64);
    inv_[mi] = v > 0.f ? 1.f / v : 0.f;
  }
  FENCE; __builtin_amdgcn_s_barrier(); FENCE;  // pass-1 readers done

  // ---- Pass 2: recompute, coalesced NT attn stores via Pf32 LDS, PV ----
  f32x4 ctx[2][4] = {};
  float* attnb = attn_out + (size_t)bh * 2048 * 2048;
  char* pF = smem + 65536 + w * 2048;  // wave-private P f32 [16 q][32 k]
  stageK(smem, 0);
  stageV(smem + 32768, 0);
  stageBias(0, 0);
  for (int kt = 0; kt < 16; ++kt) {
    if (kt + 1 < 16) {
      int nx3 = (kt + 1) % 3;
      stageK(smem + ((kt + 1) & 1) * 16384, kt + 1);
      stageV(smem + 32768 + ((kt + 1) & 1) * 16384, kt + 1);
      stageBias(nx3, kt + 1);
    }
    // FIFO: [stage(kt):9][stores(kt-1):16][stage(kt+1):9] -> 2-iter slack
    if (kt == 0) WAITV(9);
    else if (kt == 15) WAITV(16);
    else WAITV(25);
    FENCE; __builtin_amdgcn_s_barrier(); FENCE;
    const char* kl = smem + (kt & 1) * 16384;
    const char* vl = smem + 32768 + (kt & 1) * 16384;
    const float* bl = (const float*)(smem + 73728 + (kt % 3) * 512);
#pragma unroll
    for (int kc = 0; kc < 4; ++kc) {
      // hoist K fragments + bias for nb = 2kc, 2kc+1
      bf16x8 kbj[2][2];
      f32x4 cin[2];
#pragma unroll
      for (int j = 0; j < 2; ++j) {
        const int nb = kc * 2 + j;
#pragma unroll
        for (int ks = 0; ks < 2; ++ks) {
          int r = nb * 16 + c;
          int cc = (ks * 4 + g) ^ (r & 7);
          kbj[j][ks] = *reinterpret_cast<const bf16x8*>(kl + r * 128 + cc * 16);
        }
        cin[j] = *reinterpret_cast<const f32x4*>(bl + nb * 16 + g * 4);
      }
      // hoist V fragments for this 32-k chunk
      bf16x8 vb[4];
#pragma unroll
      for (int nd = 0; nd < 4; ++nd) {
        int dd = nd * 16 + c;
        int ch = (kc * 4 + g) ^ (dd & 15);
        vb[nd] = *reinterpret_cast<const bf16x8*>(vl + dd * 256 + ch * 16);
      }
#pragma unroll
      for (int mi = 0; mi < 2; ++mi) {
        // QK + exp -> Pf32 LDS (row c, chunk-XOR swizzle)
#pragma unroll
        for (int j = 0; j < 2; ++j) {
          f32x4 s = mfma16(kbj[j][0], qa[mi][0], cin[j]);
          s = mfma16(kbj[j][1], qa[mi][1], s);
          f32x4 p;
#pragma unroll
          for (int r = 0; r < 4; ++r) p[r] = exp2f(s[r]) * inv_[mi];
          *reinterpret_cast<f32x4*>(
              pF + c * 128 + (((j * 4 + g) ^ (c & 7)) * 16)) = p;
        }
        // PV A-fragment from Pf32 (k = kc*32 + g*8 .. +8), cvt to bf16
        bf16x8 pa;
        {
          f32x4 lo = *reinterpret_cast<const f32x4*>(
              pF + c * 128 + (((2 * g) ^ (c & 7)) * 16));
          f32x4 hi = *reinterpret_cast<const f32x4*>(
              pF + c * 128 + (((2 * g + 1) ^ (c & 7)) * 16));
          pa[0] = (__bf16)lo[0]; pa[1] = (__bf16)lo[1];
          pa[2] = (__bf16)lo[2]; pa[3] = (__bf16)lo[3];
          pa[4] = (__bf16)hi[0]; pa[5] = (__bf16)hi[1];
          pa[6] = (__bf16)hi[2]; pa[7] = (__bf16)hi[3];
        }
#pragma unroll
        for (int nd = 0; nd < 4; ++nd)
          ctx[mi][nd] = mfma16(pa, vb[nd], ctx[mi][nd]);
        // coalesced NT attn stores: 2 x 1 KB, each 8 rows x 128 B full lines
#pragma unroll
        for (int u = 0; u < 2; ++u) {
          int rr = u * 8 + (l >> 3);          // 0..15
          int ch = (l & 7) ^ (rr & 7);
          f32x4 pv = *reinterpret_cast<const f32x4*>(pF + rr * 128 + ch * 16);
          __builtin_nontemporal_store(
              pv, reinterpret_cast<f32x4*>(
                      attnb + (size_t)(qw + mi * 16 + rr) * 2048 + kt * 128 +
                      kc * 32 + (l & 7) * 4));
        }
      }
    }
    FENCE; __builtin_amdgcn_s_barrier(); FENCE;  // protect buf from stage(kt+2)
  }

  // ctx epilogue -> ws as [4096][1024] bf16 (row m = b*2048+s, col n = h*64+d)
  const int h = bh & 15;
#pragma unroll
  for (int mi = 0; mi < 2; ++mi)
#pragma unroll
    for (int nd = 0; nd < 4; ++nd)
#pragma unroll
      for (int r = 0; r < 4; ++r) {
        int m = b * 2048 + qw + mi * 16 + g * 4 + r;
        int n = h * 64 + nd * 16 + c;
        ctx_out[(size_t)m * 1024 + n] = (__bf16)ctx[mi][nd][r];
      }
}

// ---------------------------------------------------------------------------
extern "C" void kernel_launch(void* const* d_in, const int* in_sizes, int n_in,
                              void* d_out, int out_size, void* d_ws,
                              size_t ws_size, hipStream_t stream) {
  const float* qs = (const float*)d_in[0];
  const float* ks = (const float*)d_in[1];
  const float* vs = (const float*)d_in[2];
  const int* mask = (const int*)d_in[3];
  const float* Wq = (const float*)d_in[4];
  const float* bq = (const float*)d_in[5];
  const float* Wk = (const float*)d_in[6];
  const float* bk = (const float*)d_in[7];
  const float* Wv = (const float*)d_in[8];
  const float* bv = (const float*)d_in[9];
  const float* Wo = (const float*)d_in[10];
  const float* bo = (const float*)d_in[11];

  char* ws = (char*)d_ws;
  __bf16* Xb = (__bf16*)(ws);                    // [3][4096][1024] bf16
  __bf16* Wt = (__bf16*)(ws + 25165824);         // [4][1024][1024] bf16
  __bf16* QKV = (__bf16*)(ws + 58720256);        // [3][32][2048][64] bf16
  float* biasf = (float*)(ws + 83886080);        // [2][2048] f32
  __bf16* Vt = (__bf16*)(ws);                    // reuse X: [32][64][2048]
  __bf16* ctx = (__bf16*)(ws + 8388608);         // reuse X: [4096][1024]
  float* out = (float*)d_out;
  float* attn = out + (size_t)4194304;

  k_cvt_x<<<dim3(2048, 3), 256, 0, stream>>>(qs, ks, vs, Xb);
  k_cvt_w<<<dim3(512, 5), 256, 0, stream>>>(Wq, Wk, Wv, Wo, Wt, mask, biasf);
  k_gemm<<<dim3(256, 3), 256, 0, stream>>>(Xb, Wt, bq, bk, bv, QKV, 0);
  k_tr_v<<<dim3(2048), 256, 0, stream>>>(QKV + (size_t)2 * 4194304, Vt);
  k_attn<<<dim3(512), 256, 0, stream>>>(QKV, QKV + (size_t)4194304, Vt, biasf,
                                        attn, ctx);
  k_gemm<<<dim3(256, 1), 256, 0, stream>>>(ctx, Wt + (size_t)3 * 1048576, bo,
                                           bo, bo, d_out, 1);
}

// Round 11
// 211.260 us; speedup vs baseline: 1.3162x; 1.0680x over previous
//
#include <hip/hip_runtime.h>
#include <hip/hip_bf16.h>
#include <cstdint>

// Problem dims
#define NBATCH 2
#define NS 2048
#define NDIM 1024
#define NHEAD 16
#define NDH 64
#define NBH 32  // NBATCH*NHEAD

typedef __bf16 bf16x8 __attribute__((ext_vector_type(8)));
typedef float f32x4 __attribute__((ext_vector_type(4)));

// exp(x/8) = 2^(x * log2(e)/8); Q is pre-scaled by this in the Q-GEMM epilogue
#define QK_EXP2_SCALE 0.1803368801111244f

#define WAITV(N) asm volatile("s_waitcnt vmcnt(" #N ")" ::: "memory")
#define FENCE asm volatile("" ::: "memory")

// Direct v_exp_f32 (2^x, ~1 ULP). Plain exp2f w/o -ffast-math goes through
// OCML's multi-op precise path - pure VALU overhead at our tolerance.
#define EXP2(x) __builtin_amdgcn_exp2f(x)

static __device__ __forceinline__ f32x4 mfma16(bf16x8 a, bf16x8 b, f32x4 c) {
  return __builtin_amdgcn_mfma_f32_16x16x32_bf16(a, b, c, 0, 0, 0);
}

static __device__ __forceinline__ void gload_lds16(const void* g, void* l) {
  __builtin_amdgcn_global_load_lds(
      (const __attribute__((address_space(1))) uint32_t*)g,
      (__attribute__((address_space(3))) uint32_t*)l, 16, 0, 0);
}

// ---------------------------------------------------------------------------
// Kernel 0a: fp32 -> bf16 convert for qs/ks/vs. out: [3][4096][1024] bf16
__global__ __launch_bounds__(256) void k_cvt_x(const float* __restrict__ q,
                                               const float* __restrict__ k,
                                               const float* __restrict__ v,
                                               __bf16* __restrict__ out) {
  const float* src = blockIdx.y == 0 ? q : (blockIdx.y == 1 ? k : v);
  __bf16* dst = out + (size_t)blockIdx.y * (size_t)(4096 * 1024);
  int i = blockIdx.x * 256 + threadIdx.x;  // chunk of 8 floats
  const float4* s4 = reinterpret_cast<const float4*>(src) + (size_t)i * 2;
  float4 a = s4[0], b = s4[1];
  bf16x8 o;
  o[0] = (__bf16)a.x; o[1] = (__bf16)a.y; o[2] = (__bf16)a.z; o[3] = (__bf16)a.w;
  o[4] = (__bf16)b.x; o[5] = (__bf16)b.y; o[6] = (__bf16)b.z; o[7] = (__bf16)b.w;
  *reinterpret_cast<bf16x8*>(dst + (size_t)i * 8) = o;
}

// ---------------------------------------------------------------------------
// Kernel 0b: convert+transpose W -> Wt[n][k] bf16 (y=0..3); y==4: mask->bias.
__global__ __launch_bounds__(256) void k_cvt_w(const float* __restrict__ Wq,
                                               const float* __restrict__ Wk,
                                               const float* __restrict__ Wv,
                                               const float* __restrict__ Wo,
                                               __bf16* __restrict__ out,
                                               const int* __restrict__ mask,
                                               float* __restrict__ biasf) {
  if (blockIdx.y == 4) {
    // softmax additive bias: 0 kept, -1e30 masked.  [2][2048] f32
    int t = blockIdx.x * 256 + threadIdx.x;
    if (t < NBATCH * NS) biasf[t] = mask[t] ? 0.f : -1e30f;
    return;
  }
  const float* W = blockIdx.y == 0 ? Wq : (blockIdx.y == 1 ? Wk
                   : (blockIdx.y == 2 ? Wv : Wo));
  __bf16* dst = out + (size_t)blockIdx.y * (size_t)(1024 * 1024);
  int t = blockIdx.x * 256 + threadIdx.x;  // 0..131071
  int n = t & 1023;
  int kc = t >> 10;  // 0..127
  bf16x8 o;
#pragma unroll
  for (int j = 0; j < 8; ++j) o[j] = (__bf16)W[(size_t)(kc * 8 + j) * 1024 + n];
  *reinterpret_cast<bf16x8*>(dst + (size_t)n * 1024 + kc * 8) = o;
}

// ---------------------------------------------------------------------------
// Kernel 0c: transpose V per head: [32][2048][64] bf16 -> Vt [32][64][2048]
__global__ __launch_bounds__(256) void k_tr_v(const __bf16* __restrict__ V,
                                              __bf16* __restrict__ Vt) {
  int t = blockIdx.x * 256 + threadIdx.x;  // 0..524287
  int d = t & 63;
  int sc = (t >> 6) & 255;  // s-chunk of 8
  int bh = t >> 14;         // 0..31
  bf16x8 o;
#pragma unroll
  for (int j = 0; j < 8; ++j)
    o[j] = V[((size_t)bh * 2048 + sc * 8 + j) * 64 + d];
  *reinterpret_cast<bf16x8*>(Vt + ((size_t)bh * 64 + d) * 2048 + sc * 8) = o;
}

// ---------------------------------------------------------------------------
// GEMM: C[4096][1024] = A[4096][1024] * Bt^T + bias.  A row-major [m][k],
// Bt is [n][k] (k contiguous). 128x128 tile, BK=64, 4 waves, dbuf LDS.
// XCD-swizzled: blocks sharing an A-panel are co-resident on one XCD.
// mode 0: write bf16 to head layout [(b*16+h)][s][d], out + job*4194304;
//         job 0 (Q) additionally scaled by QK_EXP2_SCALE.
// mode 1: write fp32 row-major [m][n] (final output, non-temporal)
__global__ __launch_bounds__(256) void k_gemm(const __bf16* __restrict__ Abase,
                                              const __bf16* __restrict__ Btbase,
                                              const float* __restrict__ b0,
                                              const float* __restrict__ b1,
                                              const float* __restrict__ b2,
                                              void* __restrict__ outbase,
                                              int mode) {
  __shared__ __align__(16) char smem[65536];  // [2][A 16K | B 16K]
  const int job = blockIdx.y;
  const __bf16* A = Abase + (size_t)job * (size_t)(4096 * 1024);
  const __bf16* Bt = Btbase + (size_t)job * (size_t)(1024 * 1024);
  const float* bias = job == 0 ? b0 : (job == 1 ? b1 : b2);
  // XCD swizzle: xcd = x&7 gets mt = xcd*4 + (x>>6), all 8 nt co-resident
  const int x = blockIdx.x;
  const int mt = (x & 7) * 4 + (x >> 6);  // 0..31
  const int nt = (x >> 3) & 7;            // 0..7
  const int tid = threadIdx.x;
  const int w = tid >> 6, l = tid & 63;
  const int wr = w >> 1, wc = w & 1;

  auto stage = [&](int buf, int kt) {
    const int k0 = kt * 64;
    char* al = smem + buf * 32768;
    char* bl = al + 16384;
#pragma unroll
    for (int i = 0; i < 4; ++i) {
      int ch = tid + i * 256;  // 0..1023
      int r = ch >> 3, c = ch & 7;
      int cs = c ^ (r & 7);
      gload_lds16(A + (size_t)(mt * 128 + r) * 1024 + k0 + cs * 8, al + ch * 16);
      gload_lds16(Bt + (size_t)(nt * 128 + r) * 1024 + k0 + cs * 8, bl + ch * 16);
    }
  };

  f32x4 acc[4][4] = {};
  stage(0, 0);
  for (int kt = 0; kt < 16; ++kt) {
    __syncthreads();  // implicit vmcnt(0): stage(kt) complete for all waves
    if (kt + 1 < 16) stage((kt + 1) & 1, kt + 1);
    const char* al = smem + (kt & 1) * 32768;
    const char* bl = al + 16384;
#pragma unroll
    for (int ks = 0; ks < 2; ++ks) {
      bf16x8 af[4], bfr[4];
#pragma unroll
      for (int i = 0; i < 4; ++i) {
        int ra = wr * 64 + i * 16 + (l & 15);
        int ca = (ks * 4 + (l >> 4)) ^ (ra & 7);
        af[i] = *reinterpret_cast<const bf16x8*>(al + ra * 128 + ca * 16);
        int rb = wc * 64 + i * 16 + (l & 15);
        int cb = (ks * 4 + (l >> 4)) ^ (rb & 7);
        bfr[i] = *reinterpret_cast<const bf16x8*>(bl + rb * 128 + cb * 16);
      }
#pragma unroll
      for (int mi = 0; mi < 4; ++mi)
#pragma unroll
        for (int ni = 0; ni < 4; ++ni)
          acc[mi][ni] = mfma16(af[mi], bfr[ni], acc[mi][ni]);
    }
  }

  if (mode == 0) {
    const float sc = (job == 0) ? QK_EXP2_SCALE : 1.0f;
    __bf16* outp = (__bf16*)outbase + (size_t)job * (size_t)(NBH * NS * NDH);
#pragma unroll
    for (int mi = 0; mi < 4; ++mi)
#pragma unroll
      for (int ni = 0; ni < 4; ++ni)
#pragma unroll
        for (int r = 0; r < 4; ++r) {
          int m = mt * 128 + wr * 64 + mi * 16 + (l >> 4) * 4 + r;
          int n = nt * 128 + wc * 64 + ni * 16 + (l & 15);
          float v = (acc[mi][ni][r] + bias[n]) * sc;
          int b = m >> 11, s = m & 2047, h = n >> 6, d = n & 63;
          outp[(((size_t)(b * 16 + h)) * 2048 + s) * 64 + d] = (__bf16)v;
        }
  } else {
    float* outp = (float*)outbase;
#pragma unroll
    for (int mi = 0; mi < 4; ++mi)
#pragma unroll
      for (int ni = 0; ni < 4; ++ni)
#pragma unroll
        for (int r = 0; r < 4; ++r) {
          int m = mt * 128 + wr * 64 + mi * 16 + (l >> 4) * 4 + r;
          int n = nt * 128 + wc * 64 + ni * 16 + (l & 15);
          __builtin_nontemporal_store(acc[mi][ni][r] + bias[n],
                                      outp + (size_t)m * 1024 + n);
        }
  }
}

// ---------------------------------------------------------------------------
// Attention v9 = v8 (NT attn stores) + hardware exp2 in both passes.
// Schedule: stage-before-wait, counted vmcnt (2-iteration store slack),
// 2 barriers/kt; coalesced stores through wave-private Pf32 LDS tile.
// LDS: K dbuf @0/@16K (pass1 ring-3 @0/@16K/@32K), V dbuf @32K/@48K,
//      Pf32 per wave @64K + w*2K (8 KB), bias ring-3 @72K (3x512B).
__global__ __launch_bounds__(256, 2) void k_attn(
    const __bf16* __restrict__ Qw, const __bf16* __restrict__ Kw,
    const __bf16* __restrict__ Vt, const float* __restrict__ biasf,
    float* __restrict__ attn_out, __bf16* __restrict__ ctx_out) {
  __shared__ __align__(16) char smem[75264];
  // XCD swizzle: 512 blocks -> 64 contiguous work items (4 bh) per XCD
  const int wg = blockIdx.x;
  const int swz = (wg & 7) * 64 + (wg >> 3);
  const int qt = swz & 15;  // q-tile of 128
  const int bh = swz >> 4;  // 0..31
  const int b = bh >> 4;
  const int tid = threadIdx.x, w = tid >> 6, l = tid & 63;
  const int g = l >> 4, c = l & 15;
  const int qw = qt * 128 + w * 32;  // this wave's first q row
  const float* biasb = biasf + b * 2048;

  // Q fragments (B-operand): lane holds Q[qw+16mi+c][32ks+8g .. +8]
  bf16x8 qa[2][2];
#pragma unroll
  for (int mi = 0; mi < 2; ++mi)
#pragma unroll
    for (int ks = 0; ks < 2; ++ks)
      qa[mi][ks] = *reinterpret_cast<const bf16x8*>(
          Qw + ((size_t)bh * 2048 + qw + mi * 16 + c) * 64 + ks * 32 + g * 8);

  auto stageK = [&](char* dst, int kt) {
#pragma unroll
    for (int i = 0; i < 4; ++i) {
      int ch = tid + i * 256;  // 0..1023
      int r = ch >> 3, cc = ch & 7;
      int cs = cc ^ (r & 7);
      gload_lds16(Kw + ((size_t)bh * 2048 + kt * 128 + r) * 64 + cs * 8,
                  dst + ch * 16);
    }
  };
  auto stageV = [&](char* dst, int kt) {
#pragma unroll
    for (int i = 0; i < 4; ++i) {
      int ch = tid + i * 256;  // 0..1023
      int r = ch >> 4, cc = ch & 15;
      int cs = cc ^ (r & 15);
      gload_lds16(Vt + ((size_t)bh * 64 + r) * 2048 + kt * 128 + cs * 8,
                  dst + ch * 16);
    }
  };
  // 512 B of per-kt bias; all 4 waves write the same data (benign)
  auto stageBias = [&](int slot, int kt) {
    if (l < 32)
      gload_lds16(biasb + kt * 128 + l * 4, smem + 73728 + slot * 512);
  };

  // ---- Pass 1: masked rowsums of exp2(s+bias); K ring-3, 1 barrier/kt ----
  float rs[2] = {0.f, 0.f};
  stageK(smem, 0);
  stageBias(0, 0);
  int sl = 0;
  for (int kt = 0; kt < 16; ++kt) {
    int nx = (sl + 1 == 3) ? 0 : sl + 1;
    if (kt + 1 < 16) {
      stageK(smem + nx * 16384, kt + 1);
      stageBias(nx, kt + 1);
      WAITV(5);  // FIFO: [stage(kt):5][stage(kt+1):5] -> stage(kt) landed
    } else {
      WAITV(0);
    }
    __builtin_amdgcn_s_barrier();
    FENCE;
    const char* kl = smem + sl * 16384;
    const float* bl = (const float*)(smem + 73728 + sl * 512);
#pragma unroll
    for (int nb = 0; nb < 8; ++nb) {
      bf16x8 kb[2];
#pragma unroll
      for (int ks = 0; ks < 2; ++ks) {
        int r = nb * 16 + c;
        int cc = (ks * 4 + g) ^ (r & 7);
        kb[ks] = *reinterpret_cast<const bf16x8*>(kl + r * 128 + cc * 16);
      }
      f32x4 cinit = *reinterpret_cast<const f32x4*>(bl + nb * 16 + g * 4);
#pragma unroll
      for (int mi = 0; mi < 2; ++mi) {
        f32x4 s = mfma16(kb[0], qa[mi][0], cinit);
        s = mfma16(kb[1], qa[mi][1], s);
        rs[mi] += EXP2(s[0]) + EXP2(s[1]) + EXP2(s[2]) + EXP2(s[3]);
      }
    }
    sl = nx;
  }
  float inv_[2];
#pragma unroll
  for (int mi = 0; mi < 2; ++mi) {
    float v = rs[mi];
    v += __shfl_xor(v, 16, 64);
    v += __shfl_xor(v, 32, 64);
    inv_[mi] = v > 0.f ? 1.f / v : 0.f;
  }
  FENCE; __builtin_amdgcn_s_barrier(); FENCE;  // pass-1 readers done

  // ---- Pass 2: recompute, coalesced NT attn stores via Pf32 LDS, PV ----
  f32x4 ctx[2][4] = {};
  float* attnb = attn_out + (size_t)bh * 2048 * 2048;
  char* pF = smem + 65536 + w * 2048;  // wave-private P f32 [16 q][32 k]
  stageK(smem, 0);
  stageV(smem + 32768, 0);
  stageBias(0, 0);
  for (int kt = 0; kt < 16; ++kt) {
    if (kt + 1 < 16) {
      int nx3 = (kt + 1) % 3;
      stageK(smem + ((kt + 1) & 1) * 16384, kt + 1);
      stageV(smem + 32768 + ((kt + 1) & 1) * 16384, kt + 1);
      stageBias(nx3, kt + 1);
    }
    // FIFO: [stage(kt):9][stores(kt-1):16][stage(kt+1):9] -> 2-iter slack
    if (kt == 0) WAITV(9);
    else if (kt == 15) WAITV(16);
    else WAITV(25);
    FENCE; __builtin_amdgcn_s_barrier(); FENCE;
    const char* kl = smem + (kt & 1) * 16384;
    const char* vl = smem + 32768 + (kt & 1) * 16384;
    const float* bl = (const float*)(smem + 73728 + (kt % 3) * 512);
#pragma unroll
    for (int kc = 0; kc < 4; ++kc) {
      // hoist K fragments + bias for nb = 2kc, 2kc+1
      bf16x8 kbj[2][2];
      f32x4 cin[2];
#pragma unroll
      for (int j = 0; j < 2; ++j) {
        const int nb = kc * 2 + j;
#pragma unroll
        for (int ks = 0; ks < 2; ++ks) {
          int r = nb * 16 + c;
          int cc = (ks * 4 + g) ^ (r & 7);
          kbj[j][ks] = *reinterpret_cast<const bf16x8*>(kl + r * 128 + cc * 16);
        }
        cin[j] = *reinterpret_cast<const f32x4*>(bl + nb * 16 + g * 4);
      }
      // hoist V fragments for this 32-k chunk
      bf16x8 vb[4];
#pragma unroll
      for (int nd = 0; nd < 4; ++nd) {
        int dd = nd * 16 + c;
        int ch = (kc * 4 + g) ^ (dd & 15);
        vb[nd] = *reinterpret_cast<const bf16x8*>(vl + dd * 256 + ch * 16);
      }
#pragma unroll
      for (int mi = 0; mi < 2; ++mi) {
        // QK + exp -> Pf32 LDS (row c, chunk-XOR swizzle)
#pragma unroll
        for (int j = 0; j < 2; ++j) {
          f32x4 s = mfma16(kbj[j][0], qa[mi][0], cin[j]);
          s = mfma16(kbj[j][1], qa[mi][1], s);
          f32x4 p;
#pragma unroll
          for (int r = 0; r < 4; ++r) p[r] = EXP2(s[r]) * inv_[mi];
          *reinterpret_cast<f32x4*>(
              pF + c * 128 + (((j * 4 + g) ^ (c & 7)) * 16)) = p;
        }
        // PV A-fragment from Pf32 (k = kc*32 + g*8 .. +8), cvt to bf16
        bf16x8 pa;
        {
          f32x4 lo = *reinterpret_cast<const f32x4*>(
              pF + c * 128 + (((2 * g) ^ (c & 7)) * 16));
          f32x4 hi = *reinterpret_cast<const f32x4*>(
              pF + c * 128 + (((2 * g + 1) ^ (c & 7)) * 16));
          pa[0] = (__bf16)lo[0]; pa[1] = (__bf16)lo[1];
          pa[2] = (__bf16)lo[2]; pa[3] = (__bf16)lo[3];
          pa[4] = (__bf16)hi[0]; pa[5] = (__bf16)hi[1];
          pa[6] = (__bf16)hi[2]; pa[7] = (__bf16)hi[3];
        }
#pragma unroll
        for (int nd = 0; nd < 4; ++nd)
          ctx[mi][nd] = mfma16(pa, vb[nd], ctx[mi][nd]);
        // coalesced NT attn stores: 2 x 1 KB, each 8 rows x 128 B full lines
#pragma unroll
        for (int u = 0; u < 2; ++u) {
          int rr = u * 8 + (l >> 3);          // 0..15
          int ch = (l & 7) ^ (rr & 7);
          f32x4 pv = *reinterpret_cast<const f32x4*>(pF + rr * 128 + ch * 16);
          __builtin_nontemporal_store(
              pv, reinterpret_cast<f32x4*>(
                      attnb + (size_t)(qw + mi * 16 + rr) * 2048 + kt * 128 +
                      kc * 32 + (l & 7) * 4));
        }
      }
    }
    FENCE; __builtin_amdgcn_s_barrier(); FENCE;  // protect buf from stage(kt+2)
  }

  // ctx epilogue -> ws as [4096][1024] bf16 (row m = b*2048+s, col n = h*64+d)
  const int h = bh & 15;
#pragma unroll
  for (int mi = 0; mi < 2; ++mi)
#pragma unroll
    for (int nd = 0; nd < 4; ++nd)
#pragma unroll
      for (int r = 0; r < 4; ++r) {
        int m = b * 2048 + qw + mi * 16 + g * 4 + r;
        int n = h * 64 + nd * 16 + c;
        ctx_out[(size_t)m * 1024 + n] = (__bf16)ctx[mi][nd][r];
      }
}

// ---------------------------------------------------------------------------
extern "C" void kernel_launch(void* const* d_in, const int* in_sizes, int n_in,
                              void* d_out, int out_size, void* d_ws,
                              size_t ws_size, hipStream_t stream) {
  const float* qs = (const float*)d_in[0];
  const float* ks = (const float*)d_in[1];
  const float* vs = (const float*)d_in[2];
  const int* mask = (const int*)d_in[3];
  const float* Wq = (const float*)d_in[4];
  const float* bq = (const float*)d_in[5];
  const float* Wk = (const float*)d_in[6];
  const float* bk = (const float*)d_in[7];
  const float* Wv = (const float*)d_in[8];
  const float* bv = (const float*)d_in[9];
  const float* Wo = (const float*)d_in[10];
  const float* bo = (const float*)d_in[11];

  char* ws = (char*)d_ws;
  __bf16* Xb = (__bf16*)(ws);                    // [3][4096][1024] bf16
  __bf16* Wt = (__bf16*)(ws + 25165824);         // [4][1024][1024] bf16
  __bf16* QKV = (__bf16*)(ws + 58720256);        // [3][32][2048][64] bf16
  float* biasf = (float*)(ws + 83886080);        // [2][2048] f32
  __bf16* Vt = (__bf16*)(ws);                    // reuse X: [32][64][2048]
  __bf16* ctx = (__bf16*)(ws + 8388608);         // reuse X: [4096][1024]
  float* out = (float*)d_out;
  float* attn = out + (size_t)4194304;

  k_cvt_x<<<dim3(2048, 3), 256, 0, stream>>>(qs, ks, vs, Xb);
  k_cvt_w<<<dim3(512, 5), 256, 0, stream>>>(Wq, Wk, Wv, Wo, Wt, mask, biasf);
  k_gemm<<<dim3(256, 3), 256, 0, stream>>>(Xb, Wt, bq, bk, bv, QKV, 0);
  k_tr_v<<<dim3(2048), 256, 0, stream>>>(QKV + (size_t)2 * 4194304, Vt);
  k_attn<<<dim3(512), 256, 0, stream>>>(QKV, QKV + (size_t)4194304, Vt, biasf,
                                        attn, ctx);
  k_gemm<<<dim3(256, 1), 256, 0, stream>>>(ctx, Wt + (size_t)3 * 1048576, bo,
                                           bo, bo, d_out, 1);
}